// Round 8
// baseline (179.661 us; speedup 1.0000x reference)
//
#include <hip/hip_runtime.h>

#define SB 2048
#define DM 1024
#define N3 3072

typedef short bf16x8 __attribute__((ext_vector_type(8)));
typedef float f32x4 __attribute__((ext_vector_type(4)));
typedef unsigned short u16;

#define MFMA16(a, b, c) __builtin_amdgcn_mfma_f32_16x16x32_bf16(a, b, c, 0, 0, 0)

typedef const __attribute__((address_space(1))) unsigned int* gptr_t;
typedef __attribute__((address_space(3))) unsigned int* lptr_t;

__device__ __forceinline__ u16 f2bf(float x) {
  union { float f; unsigned u; } c; c.f = x;
  unsigned r = c.u + 0x7FFFu + ((c.u >> 16) & 1u);
  return (u16)(r >> 16);
}
__device__ __forceinline__ float bf2f(u16 x) {
  union { unsigned u; float f; } c; c.u = ((unsigned)x) << 16;
  return c.f;
}

// ---------------- 1) x fp32 -> bf16 ----------------
__global__ void k_cvt_x(const float* __restrict__ x, u16* __restrict__ xb, int n4) {
  int i = blockIdx.x * blockDim.x + threadIdx.x;
  if (i >= n4) return;
  float4 v = ((const float4*)x)[i];
  ushort4 o;
  o.x = f2bf(v.x); o.y = f2bf(v.y); o.z = f2bf(v.z); o.w = f2bf(v.w);
  ((ushort4*)xb)[i] = o;
}

// ---------------- 2) W [1024][3072] f32 -> Wt [3072][1024] bf16 ----------------
__global__ void k_cvt_wt(const float* __restrict__ W, u16* __restrict__ Wt) {
  __shared__ float t[32][33];
  int n0 = blockIdx.x * 32;
  int k0 = blockIdx.y * 32;
  int tx = threadIdx.x & 31, ty = threadIdx.x >> 5;
#pragma unroll
  for (int r = 0; r < 4; ++r)
    t[ty + r * 8][tx] = W[(size_t)(k0 + ty + r * 8) * N3 + n0 + tx];
  __syncthreads();
#pragma unroll
  for (int r = 0; r < 4; ++r)
    Wt[(size_t)(n0 + ty + r * 8) * DM + k0 + tx] = f2bf(t[tx][ty + r * 8]);
}

// ---------------- 3) QKV GEMM v2: counted-vmcnt 4-buffer pipeline ----------------
// BM=128, BN=256, BK=32, 8 waves (2Mx4N, 64x64 per wave), grid 64x12=768 (=3 CU rounds).
// LDS: A 4x[128][32], B 4x[256][32] = 96 KB. Staging targets buf[(i+3)&3], which was
// retired at barrier i-1 -> no LDS WAR by construction. vmcnt(6) steady state keeps
// 2 K-tiles of loads in flight across barriers (T4). 16B-slot swizzle on BOTH the
// global source column and the ds_read address (rule 21) -> 2-way banks (free).
__global__ __launch_bounds__(512, 2) void k_gemm(const u16* __restrict__ xb,
                                                 const u16* __restrict__ wt,
                                                 u16* __restrict__ qk,
                                                 u16* __restrict__ vt) {
  __shared__ u16 Asl[4][128 * 32];
  __shared__ u16 Bsl[4][256 * 32];
  int bid = blockIdx.x;
  int swz = (bid & 7) * 96 + (bid >> 3);     // bijective XCD swizzle (768 % 8 == 0)
  int mt = swz / 12, nt = swz % 12;
  int m0 = mt * 128, n0 = nt * 256;
  int tid = threadIdx.x, lane = tid & 63, wid = tid >> 6;
  int lr = lane & 15, kg = lane >> 4;
  int wm = (wid >> 2) * 64, wn = (wid & 3) * 64;

  // staging source descriptors (inverse swizzle on global col)
  int arow = tid >> 2, aseg = tid & 3;
  const u16* aptr = xb + (size_t)(m0 + arow) * 1024 + ((aseg - (arow >> 1)) & 3) * 8;
  int brow0 = tid >> 2, brow1 = 128 + (tid >> 2), bseg = tid & 3;
  const u16* bptr0 = wt + (size_t)(n0 + brow0) * 1024 + ((bseg - (brow0 >> 1)) & 3) * 8;
  const u16* bptr1 = wt + (size_t)(n0 + brow1) * 1024 + ((bseg - (brow1 >> 1)) & 3) * 8;

  f32x4 acc[4][4] = {};

#define STAGE_A(kt) __builtin_amdgcn_global_load_lds( \
    (gptr_t)(const void*)(aptr + (kt) * 32), (lptr_t)(void*)&Asl[(kt) & 3][tid * 8], 16, 0, 0)
#define STAGE_B(kt) do { \
    __builtin_amdgcn_global_load_lds((gptr_t)(const void*)(bptr0 + (kt) * 32), \
        (lptr_t)(void*)&Bsl[(kt) & 3][tid * 8], 16, 0, 0); \
    __builtin_amdgcn_global_load_lds((gptr_t)(const void*)(bptr1 + (kt) * 32), \
        (lptr_t)(void*)&Bsl[(kt) & 3][4096 + tid * 8], 16, 0, 0); } while (0)

  STAGE_A(0); STAGE_B(0);
  STAGE_A(1); STAGE_B(1);
  STAGE_A(2); STAGE_B(2);
  asm volatile("s_waitcnt vmcnt(6)" ::: "memory");   // ktile 0 landed
  __builtin_amdgcn_s_barrier();

  for (int i = 0; i < 32; ++i) {
    int buf = i & 3;
    if (i <= 28) STAGE_A(i + 3);
    bf16x8 bfr[4], afr[4];
#pragma unroll
    for (int j = 0; j < 4; ++j) {
      int row = wn + j * 16 + lr;
      int slot = (kg + (row >> 1)) & 3;
      bfr[j] = *(const bf16x8*)&Bsl[buf][row * 32 + slot * 8];
    }
#pragma unroll
    for (int q = 0; q < 4; ++q) {
      int row = wm + q * 16 + lr;
      int slot = (kg + (row >> 1)) & 3;
      afr[q] = *(const bf16x8*)&Asl[buf][row * 32 + slot * 8];
    }
    if (i <= 28) STAGE_B(i + 3);
    __builtin_amdgcn_s_setprio(1);
#pragma unroll
    for (int q = 0; q < 4; ++q)
#pragma unroll
      for (int j = 0; j < 4; ++j)
        acc[q][j] = MFMA16(afr[q], bfr[j], acc[q][j]);
    __builtin_amdgcn_s_setprio(0);
    if (i < 31) {
      if (i <= 28)      asm volatile("s_waitcnt vmcnt(6)" ::: "memory");  // k(i+1) landed
      else if (i == 29) asm volatile("s_waitcnt vmcnt(3)" ::: "memory");
      else              asm volatile("s_waitcnt vmcnt(0)" ::: "memory");
      __builtin_amdgcn_s_barrier();
    }
  }
#undef STAGE_A
#undef STAGE_B

  if (n0 < 2048) {
#pragma unroll
    for (int q = 0; q < 4; ++q)
#pragma unroll
      for (int j = 0; j < 4; ++j)
#pragma unroll
        for (int r = 0; r < 4; ++r)
          qk[(size_t)(m0 + wm + q * 16 + kg * 4 + r) * 2048 + n0 + wn + j * 16 + lr] = f2bf(acc[q][j][r]);
  } else {
#pragma unroll
    for (int q = 0; q < 4; ++q)
#pragma unroll
      for (int j = 0; j < 4; ++j)
#pragma unroll
        for (int r = 0; r < 4; ++r) {
          int m = m0 + wm + q * 16 + kg * 4 + r;
          int d = n0 + wn + j * 16 + lr - 2048;
          vt[(size_t)((m >> 11) * DM + d) * SB + (m & 2047)] = f2bf(acc[q][j][r]);
        }
  }
}

// ---------------- 4) S = Q K^T / 32, block-triangular (kt >= qt), bf16 ----------------
__global__ __launch_bounds__(256, 2) void k_qkt(const u16* __restrict__ qk,
                                                u16* __restrict__ S) {
  __shared__ u16 As[2][128 * 32];
  __shared__ u16 Bs[2][128 * 32];
  int bid = blockIdx.x;
  int b = bid & 3;
  int pi = bid >> 2;                 // 0..135 -> (qt, kt) with kt >= qt
  int qt = 0;
  while (true) { int cnt = 16 - qt; if (pi < cnt) break; pi -= cnt; ++qt; }
  int kt = qt + pi;
  int m0 = qt * 128, n0 = kt * 128;
  int tid = threadIdx.x, lane = tid & 63, wid = tid >> 6;
  int lr = lane & 15, lg = lane >> 4;
  int wm = (wid >> 1) * 64, wn = (wid & 1) * 64;
  int ca = lane >> 2;
  int cb = (lane & 3) * 8;
  const u16* Qb = qk + (size_t)(b * SB) * 2048;
  f32x4 acc[4][4] = {};
  int p = 0;
  for (int kk = 0; kk < 1024; kk += 32) {
#pragma unroll
    for (int j = 0; j < 2; ++j) {
      int chunk = wid * 2 + j;
      const u16* ga = Qb + (size_t)(m0 + chunk * 16 + ca) * 2048 + kk + cb;          // Q
      const u16* gb = Qb + (size_t)(n0 + chunk * 16 + ca) * 2048 + 1024 + kk + cb;   // K
      __builtin_amdgcn_global_load_lds((gptr_t)(const void*)ga, (lptr_t)(void*)&As[p][chunk * 512], 16, 0, 0);
      __builtin_amdgcn_global_load_lds((gptr_t)(const void*)gb, (lptr_t)(void*)&Bs[p][chunk * 512], 16, 0, 0);
    }
    __syncthreads();
    bf16x8 af[4], bff[4];
#pragma unroll
    for (int i = 0; i < 4; ++i) af[i] = *(const bf16x8*)&As[p][(wm + i * 16 + lr) * 32 + lg * 8];
#pragma unroll
    for (int j = 0; j < 4; ++j) bff[j] = *(const bf16x8*)&Bs[p][(wn + j * 16 + lr) * 32 + lg * 8];
#pragma unroll
    for (int i = 0; i < 4; ++i)
#pragma unroll
      for (int j = 0; j < 4; ++j)
        acc[i][j] = MFMA16(af[i], bff[j], acc[i][j]);
    __syncthreads();
    p ^= 1;
  }
  u16* Sb = S + (size_t)(b * SB) * 2048;
#pragma unroll
  for (int i = 0; i < 4; ++i)
#pragma unroll
    for (int j = 0; j < 4; ++j)
#pragma unroll
      for (int r = 0; r < 4; ++r) {
        int q = m0 + wm + i * 16 + lg * 4 + r;
        int k = n0 + wn + j * 16 + lr;
        float v = acc[i][j][r] * 0.03125f;
        if (k < q) v = -1e30f;         // keep key >= query (anti-causal)
        Sb[(size_t)q * 2048 + k] = f2bf(v);
      }
}

// ---------------- 5) row softmax in-place on S (valid range k >= qt*128) ----------------
__global__ void k_sm(u16* __restrict__ S) {
  __shared__ float rmax[4], rsum[4];
  int row = blockIdx.x;              // b*2048 + q
  int q = row & 2047;
  int k0 = (q >> 7) << 7;
  int len = 2048 - k0;               // multiple of 128
  int tid = threadIdx.x;
  u16* rp = S + (size_t)row * 2048 + k0;
  int nv = len >> 3;
  bool act = tid < nv;
  float v[8];
  float mx = -1e30f;
  if (act) {
    bf16x8 x = *(const bf16x8*)(rp + tid * 8);
#pragma unroll
    for (int j = 0; j < 8; ++j) { v[j] = bf2f((u16)x[j]); mx = fmaxf(mx, v[j]); }
  }
#pragma unroll
  for (int off = 32; off; off >>= 1) mx = fmaxf(mx, __shfl_xor(mx, off, 64));
  int wv = tid >> 6;
  if ((tid & 63) == 0) rmax[wv] = mx;
  __syncthreads();
  mx = fmaxf(fmaxf(rmax[0], rmax[1]), fmaxf(rmax[2], rmax[3]));
  float sum = 0.f;
  if (act) {
#pragma unroll
    for (int j = 0; j < 8; ++j) { v[j] = __expf(v[j] - mx); sum += v[j]; }
  }
#pragma unroll
  for (int off = 32; off; off >>= 1) sum += __shfl_xor(sum, off, 64);
  if ((tid & 63) == 0) rsum[wv] = sum;
  __syncthreads();
  float inv = 1.f / ((rsum[0] + rsum[1]) + (rsum[2] + rsum[3]));
  if (act) {
    bf16x8 o;
#pragma unroll
    for (int j = 0; j < 8; ++j) o[j] = (short)f2bf(v[j] * inv);
    *(bf16x8*)(rp + tid * 8) = o;
  }
}

// ---------------- 6) O = P V, block-triangular variable-K, f32 out ----------------
__global__ __launch_bounds__(256, 2) void k_pv(const u16* __restrict__ P,
                                               const u16* __restrict__ vt,
                                               float* __restrict__ out) {
  __shared__ u16 As[2][128 * 32];
  __shared__ u16 Bs[2][128 * 32];
  int bid = blockIdx.x;
  int qt = bid >> 5;                 // heavy-first (qt=0 has longest K-loop)
  int rem = bid & 31;
  int dt = rem >> 2;
  int b = rem & 3;
  int m0 = qt * 128, n0 = dt * 128;
  int tid = threadIdx.x, lane = tid & 63, wid = tid >> 6;
  int lr = lane & 15, lg = lane >> 4;
  int wm = (wid >> 1) * 64, wn = (wid & 1) * 64;
  int ca = lane >> 2;
  int cb = (lane & 3) * 8;
  const u16* Pb = P + (size_t)(b * SB) * 2048;
  const u16* Vb = vt + (size_t)(b * DM) * 2048;
  f32x4 acc[4][4] = {};
  int p = 0;
  for (int kk = m0; kk < 2048; kk += 32) {
#pragma unroll
    for (int j = 0; j < 2; ++j) {
      int chunk = wid * 2 + j;
      const u16* ga = Pb + (size_t)(m0 + chunk * 16 + ca) * 2048 + kk + cb;
      const u16* gb = Vb + (size_t)(n0 + chunk * 16 + ca) * 2048 + kk + cb;
      __builtin_amdgcn_global_load_lds((gptr_t)(const void*)ga, (lptr_t)(void*)&As[p][chunk * 512], 16, 0, 0);
      __builtin_amdgcn_global_load_lds((gptr_t)(const void*)gb, (lptr_t)(void*)&Bs[p][chunk * 512], 16, 0, 0);
    }
    __syncthreads();
    bf16x8 af[4], bff[4];
#pragma unroll
    for (int i = 0; i < 4; ++i) af[i] = *(const bf16x8*)&As[p][(wm + i * 16 + lr) * 32 + lg * 8];
#pragma unroll
    for (int j = 0; j < 4; ++j) bff[j] = *(const bf16x8*)&Bs[p][(wn + j * 16 + lr) * 32 + lg * 8];
#pragma unroll
    for (int i = 0; i < 4; ++i)
#pragma unroll
      for (int j = 0; j < 4; ++j)
        acc[i][j] = MFMA16(af[i], bff[j], acc[i][j]);
    __syncthreads();
    p ^= 1;
  }
#pragma unroll
  for (int i = 0; i < 4; ++i)
#pragma unroll
    for (int j = 0; j < 4; ++j)
#pragma unroll
      for (int r = 0; r < 4; ++r)
        out[(size_t)(b * SB + m0 + wm + i * 16 + lg * 4 + r) * DM + n0 + wn + j * 16 + lr] = acc[i][j][r];
}

extern "C" void kernel_launch(void* const* d_in, const int* in_sizes, int n_in,
                              void* d_out, int out_size, void* d_ws, size_t ws_size,
                              hipStream_t stream) {
  const float* x = (const float*)d_in[0];
  const float* W = (const float*)d_in[1];
  float* out = (float*)d_out;
  char* ws = (char*)d_ws;
  // layout (80 MB total):
  u16* qk = (u16*)(ws);                  // 32 MB : [8192][2048] bf16 (Q | K)
  u16* vt = (u16*)(ws + 33554432);       // 16 MB : [4][1024][2048] bf16 (V^T)
  u16* xb = (u16*)(ws + 50331648);       // 16 MB : x bf16 (dead after k_gemm)
  u16* wt = (u16*)(ws + 67108864);       //  6 MB : W^T bf16 (dead after k_gemm)
  u16* S  = (u16*)(ws + 50331648);       // 32 MB : scores/P bf16, reuses xb+wt region

  k_cvt_x<<<8192, 256, 0, stream>>>(x, xb, 2097152);
  dim3 gw(96, 32);
  k_cvt_wt<<<gw, 256, 0, stream>>>(W, wt);
  k_gemm<<<768, 512, 0, stream>>>(xb, wt, qk, vt);
  k_qkt<<<544, 256, 0, stream>>>(qk, S);
  k_sm<<<8192, 256, 0, stream>>>(S);
  k_pv<<<512, 256, 0, stream>>>(S, vt, out);
}